// Round 11
// baseline (498.047 us; speedup 1.0000x reference)
//
#include <hip/hip_runtime.h>
#include <hip/hip_bf16.h>
#include <math.h>

// Problem constants: B=4, C=D=256, H=W=128, HID=1024, N = B*H*W = 65536.
#define NPIX  65536
#define CCH   256
#define HWSZ  16384
#define WIDTH 128
#define HID   1024

typedef unsigned short u16;
typedef __bf16 bf16x8 __attribute__((ext_vector_type(8)));
typedef float  floatx4 __attribute__((ext_vector_type(4)));

__device__ __forceinline__ float bf2f(u16 u) {
  union { unsigned int i; float f; } c; c.i = ((unsigned int)u) << 16; return c.f;
}
__device__ __forceinline__ float bflo(unsigned int u) {
  union { unsigned int i; float f; } c; c.i = u << 16; return c.f;
}
__device__ __forceinline__ float bfhi(unsigned int u) {
  union { unsigned int i; float f; } c; c.i = u & 0xffff0000u; return c.f;
}
__device__ __forceinline__ u16 f2bf(float f) {
  union { float f; unsigned int i; } c; c.f = f;
  unsigned int x = c.i;
  x += 0x7fffu + ((x >> 16) & 1u);   // round-to-nearest-even
  return (u16)(x >> 16);
}
__device__ __forceinline__ unsigned int packbf(float lo, float hi) {
  return ((unsigned int)f2bf(hi) << 16) | (unsigned int)f2bf(lo);
}
__device__ __forceinline__ float fast_rcp(float x) {
  float r; asm("v_rcp_f32 %0, %1" : "=v"(r) : "v"(x)); return r;
}
__device__ __forceinline__ float fast_exp2(float x) {
  float r; asm("v_exp_f32 %0, %1" : "=v"(r) : "v"(x)); return r;   // 2^x
}
// gelu, tanh-approx form, algebraically = 0.5x(1+tanh(0.79788(x+0.044715x^3)))
//   = x * sigmoid(2t) = x / (1 + 2^(-x*(a*x^2 + b))),  a,b fold in 2*log2(e).
__device__ __forceinline__ float gelu_fast(float x) {
  const float u = x * x;
  const float s = x * fmaf(0.1029432f, u, 2.3022082f);
  const float e = fast_exp2(-s);      // v_exp_f32
  return x * fast_rcp(1.0f + e);      // v_rcp_f32 (no fdiv expansion)
}

// async global->LDS, 16B per lane; LDS dest is wave-uniform base + lane*16.
__device__ __forceinline__ void async16(const void* g, void* l) {
  __builtin_amdgcn_global_load_lds(
      (const __attribute__((address_space(1))) void*)g,
      (__attribute__((address_space(3))) void*)l, 16, 0, 0);
}

// ---------------------------------------------------------------------------
// Weight fp32 [K,N] -> fragment-major bf16 blob:
// unit u = g*(K/32) + kb   (g = 16-col group, kb = 32-k block); unit = 512 u16.
// dst[u*512 + lane*8 + e] = bf16(src[(kb*32 + (lane>>4)*8 + e)*N + g*16 + (lane&15)])
__global__ __launch_bounds__(256) void wfrag_kernel(
    const float* __restrict__ src, u16* __restrict__ dst, int N, int K) {
  const int tid = threadIdx.x;
  const int u = blockIdx.x * 4 + (tid >> 6);
  const int lane = tid & 63, quad = lane >> 4, l16 = lane & 15;
  const int K32 = K >> 5;
  const int g = u / K32, kb = u - g * K32;
  const int n = g * 16 + l16;
  const int k0 = kb * 32 + quad * 8;
  u16 tmp[8];
#pragma unroll
  for (int e = 0; e < 8; e++) tmp[e] = f2bf(src[(size_t)(k0 + e) * N + n]);
  *(bf16x8*)(dst + ((size_t)u * 64 + lane) * 8) = *(bf16x8*)tmp;
}

__global__ __launch_bounds__(256) void concat_bias_kernel(
    const float* __restrict__ bq, const float* __restrict__ bk,
    const float* __restrict__ bv, float* __restrict__ dst) {
  const int i = blockIdx.x * 256 + threadIdx.x;   // grid 3
  if (i < 256) dst[i] = bq[i];
  else if (i < 512) dst[i] = bk[i - 256];
  else if (i < 768) dst[i] = bv[i - 512];
}

// ---------------------------------------------------------------------------
// LayerNorm1: x [B,C,H,W] fp32 -> n1 [N,256] bf16
__global__ __launch_bounds__(256) void ln1_kernel(
    const float* __restrict__ x, const float* __restrict__ g,
    const float* __restrict__ bb, u16* __restrict__ n1) {
  __shared__ float sx[32][257];
  __shared__ float sred[16][32];
  __shared__ float sm[32], sr[32];
  const int tx = threadIdx.x;
  const int p0 = blockIdx.x * 32;
  {
    const int pix = tx & 31, cpart = tx >> 5;
    const int p = p0 + pix;
    const int b = p >> 14, hw = p & (HWSZ - 1);
    const float* xb = x + ((size_t)b * CCH) * HWSZ + hw;
    float s = 0.f, s2 = 0.f;
#pragma unroll 4
    for (int i = 0; i < 32; i++) {
      const int c = cpart * 32 + i;
      const float v = xb[(size_t)c * HWSZ];
      sx[pix][c] = v;
      s += v; s2 += v * v;
    }
    sred[cpart][pix] = s; sred[8 + cpart][pix] = s2;
  }
  __syncthreads();
  if (tx < 32) {
    float s = 0.f, s2 = 0.f;
#pragma unroll
    for (int j = 0; j < 8; j++) { s += sred[j][tx]; s2 += sred[8 + j][tx]; }
    const float m = s * (1.0f / 256.0f);
    const float var = s2 * (1.0f / 256.0f) - m * m;
    sm[tx] = m; sr[tx] = rsqrtf(var + 1e-5f);
  }
  __syncthreads();
  const float gc = g[tx], bc = bb[tx];
#pragma unroll 4
  for (int i = 0; i < 32; i++) {
    const float v = (sx[i][tx] - sm[i]) * sr[i] * gc + bc;
    n1[(size_t)(p0 + i) * CCH + tx] = f2bf(v);
  }
}

// ---------------------------------------------------------------------------
// Residual + LayerNorm2: x1 = x + attn (fp32 out), n2 = LN(x1) bf16
__global__ __launch_bounds__(256) void res_ln2_kernel(
    const float* __restrict__ x, const u16* __restrict__ attn,
    const float* __restrict__ g, const float* __restrict__ bb,
    float* __restrict__ x1, u16* __restrict__ n2) {
  __shared__ float sx[32][257];
  __shared__ float sred[16][32];
  __shared__ float sm[32], sr[32];
  const int tx = threadIdx.x;
  const int p0 = blockIdx.x * 32;
  {
    const int pix = tx & 31, cpart = tx >> 5;
    const int p = p0 + pix;
    const int b = p >> 14, hw = p & (HWSZ - 1);
    const float* xb = x + ((size_t)b * CCH) * HWSZ + hw;
#pragma unroll 4
    for (int i = 0; i < 32; i++) {
      const int c = cpart * 32 + i;
      sx[pix][c] = xb[(size_t)c * HWSZ];
    }
  }
  __syncthreads();
#pragma unroll 4
  for (int i = 0; i < 32; i++) {
    const float v = sx[i][tx] + bf2f(attn[(size_t)(p0 + i) * CCH + tx]);
    sx[i][tx] = v;
    x1[(size_t)(p0 + i) * CCH + tx] = v;
  }
  __syncthreads();
  {
    const int pix = tx & 31, cpart = tx >> 5;
    float s = 0.f, s2 = 0.f;
#pragma unroll 4
    for (int i = 0; i < 32; i++) {
      const float v = sx[pix][cpart * 32 + i];
      s += v; s2 += v * v;
    }
    sred[cpart][pix] = s; sred[8 + cpart][pix] = s2;
  }
  __syncthreads();
  if (tx < 32) {
    float s = 0.f, s2 = 0.f;
#pragma unroll
    for (int j = 0; j < 8; j++) { s += sred[j][tx]; s2 += sred[8 + j][tx]; }
    const float m = s * (1.0f / 256.0f);
    const float var = s2 * (1.0f / 256.0f) - m * m;
    sm[tx] = m; sr[tx] = rsqrtf(var + 1e-5f);
  }
  __syncthreads();
  const float gc = g[tx], bc = bb[tx];
#pragma unroll 4
  for (int i = 0; i < 32; i++) {
    const float v = (sx[i][tx] - sm[i]) * sr[i] * gc + bc;
    n2[(size_t)(p0 + i) * CCH + tx] = f2bf(v);
  }
}

// ---------------------------------------------------------------------------
// 3x3 neighborhood attention over fused qkv [N,768] (q|k|v per row).
__global__ __launch_bounds__(256) void attn_kernel(
    const u16* __restrict__ qkv, u16* __restrict__ attn) {
  const int tid = threadIdx.x;
  const int wave = tid >> 6, lane = tid & 63;
  const int p = blockIdx.x * 4 + wave;
  const int hw = p & (HWSZ - 1);
  const int hh = hw >> 7, ww = hw & (WIDTH - 1);
  const u16* rowp = qkv + (size_t)p * 768 + lane * 4;
  const uint2 qr = *(const uint2*)rowp;
  const float qf0 = bflo(qr.x), qf1 = bfhi(qr.x);
  const float qf2 = bflo(qr.y), qf3 = bfhi(qr.y);
  float sc[9];
#pragma unroll
  for (int n = 0; n < 9; n++) {
    const int dy = n / 3 - 1, dx = n % 3 - 1;
    const int y = hh + dy, x2 = ww + dx;
    float s = -1e30f;
    if (y >= 0 && y < 128 && x2 >= 0 && x2 < 128) {   // wave-uniform branch
      const uint2 kr = *(const uint2*)(rowp + 256 + (dy * WIDTH + dx) * 768);
      float d = qf0 * bflo(kr.x) + qf1 * bfhi(kr.x)
              + qf2 * bflo(kr.y) + qf3 * bfhi(kr.y);
#pragma unroll
      for (int o = 32; o >= 1; o >>= 1) d += __shfl_xor(d, o, 64);
      s = d * 0.0625f;   // 1/sqrt(256)
    }
    sc[n] = s;
  }
  float mx = sc[0];
#pragma unroll
  for (int n = 1; n < 9; n++) mx = fmaxf(mx, sc[n]);
  float wgt[9], wsum = 0.f;
#pragma unroll
  for (int n = 0; n < 9; n++) { wgt[n] = __expf(sc[n] - mx); wsum += wgt[n]; }
  const float inv = 1.0f / wsum;
  float a0 = 0.f, a1 = 0.f, a2 = 0.f, a3 = 0.f;
#pragma unroll
  for (int n = 0; n < 9; n++) {
    const int dy = n / 3 - 1, dx = n % 3 - 1;
    const int y = hh + dy, x2 = ww + dx;
    if (y >= 0 && y < 128 && x2 >= 0 && x2 < 128) {
      const uint2 vr = *(const uint2*)(rowp + 512 + (dy * WIDTH + dx) * 768);
      const float wn = wgt[n] * inv;
      a0 += wn * bflo(vr.x); a1 += wn * bfhi(vr.x);
      a2 += wn * bflo(vr.y); a3 += wn * bfhi(vr.y);
    }
  }
  uint2 o;
  o.x = ((unsigned int)f2bf(a1) << 16) | (unsigned int)f2bf(a0);
  o.y = ((unsigned int)f2bf(a3) << 16) | (unsigned int)f2bf(a2);
  *(uint2*)(attn + (size_t)p * CCH + lane * 4) = o;
}

// ---------------------------------------------------------------------------
// GEMM with B in double-buffered LDS (staged via global_load_lds) and whole-K
// A in registers. 128-row blocks (4 waves x 32 rows), K=256, 64-col chunks.
// Swapped MFMA operands -> D^T layout; dwordx2 packed stores.
// Counted vmcnt(8) barriers (verified R9). Used for the fused QKV GEMM.
template <int NCH, int NST, int EPI>
__global__ __launch_bounds__(256, 3) void gemm_blds(
    const u16* __restrict__ A, const u16* __restrict__ wf,
    const float* __restrict__ bias, u16* __restrict__ outb) {
  __shared__ u16 sB[2][16384];    // 2 x 32 KB
  const int tid  = threadIdx.x;
  const int wave = tid >> 6, lane = tid & 63;
  const int quad = lane >> 4, l16 = lane & 15;
  const int m0 = blockIdx.x * 128 + wave * 32;

  // A fragments: rows m0..m0+31, full K=256. 64 VGPRs.
  const u16* aRow = A + (size_t)(m0 + l16) * CCH + quad * 8;
  bf16x8 afr[2][8];
#pragma unroll
  for (int mi = 0; mi < 2; mi++)
#pragma unroll
    for (int ks = 0; ks < 8; ks++)
      afr[mi][ks] = *(const bf16x8*)(aRow + (size_t)mi * 16 * CCH + ks * 32);

  // output row pointers (transposed-acc layout: row = m0 + mi*16 + l16)
  u16* rowPtr0 = outb + (size_t)(m0 + l16) * NST;
  u16* rowPtr1 = rowPtr0 + (size_t)16 * NST;

  auto stage = [&](int ch, int buf) {
    const u16* g = wf + (size_t)ch * 16384;    // chunk = 4 groups x 8 kb = 32 KB
#pragma unroll
    for (int i = 0; i < 8; i++)
      async16(g + i * 2048 + tid * 8, &sB[buf][i * 2048 + tid * 8]);
  };

  stage(0, 0);
#pragma unroll 1
  for (int ch = 0; ch < NCH; ++ch) {
    if (ch == 0) asm volatile("s_waitcnt vmcnt(0)" ::: "memory");
    else         asm volatile("s_waitcnt vmcnt(8)" ::: "memory");
    __builtin_amdgcn_s_barrier();
    __builtin_amdgcn_sched_barrier(0);
    floatx4 bs4pre[4];
#pragma unroll
    for (int gi = 0; gi < 4; gi++)
      bs4pre[gi] = *(const floatx4*)&bias[ch * 64 + gi * 16 + quad * 4];
    if (ch + 1 < NCH) stage(ch + 1, (ch + 1) & 1);
    __builtin_amdgcn_sched_barrier(0);
    const u16* sb = sB[ch & 1];
    floatx4 acc[2][4];
#pragma unroll
    for (int mi = 0; mi < 2; mi++)
#pragma unroll
      for (int gi = 0; gi < 4; gi++) acc[mi][gi] = (floatx4){0.f, 0.f, 0.f, 0.f};
#pragma unroll
    for (int ks = 0; ks < 8; ks++) {
      bf16x8 bfr[4];
#pragma unroll
      for (int gi = 0; gi < 4; gi++)
        bfr[gi] = *(const bf16x8*)&sb[(gi * 8 + ks) * 512 + lane * 8];
#pragma unroll
      for (int mi = 0; mi < 2; mi++)
#pragma unroll
        for (int gi = 0; gi < 4; gi++)
          acc[mi][gi] = __builtin_amdgcn_mfma_f32_16x16x32_bf16(
              bfr[gi], afr[mi][ks], acc[mi][gi], 0, 0, 0);   // swapped -> D^T
    }
#pragma unroll
    for (int gi = 0; gi < 4; gi++) {
      const int colb = ch * 64 + gi * 16 + quad * 4;
      const floatx4 bs4 = bs4pre[gi];
#pragma unroll
      for (int mi = 0; mi < 2; mi++) {
        float v[4];
#pragma unroll
        for (int r = 0; r < 4; r++) {
          float val = acc[mi][gi][r] + bs4[r];
          if constexpr (EPI == 1) val = gelu_fast(val);
          v[r] = val;
        }
        uint2 w;
        w.x = packbf(v[0], v[1]);
        w.y = packbf(v[2], v[3]);
        *(uint2*)((mi == 0 ? rowPtr0 : rowPtr1) + colb) = w;
      }
    }
  }
}

// ---------------------------------------------------------------------------
// FUSED MLP: out = x1 + (gelu(n2 @ W1 + b1)) @ W2 + b2, transposed store.
// h never touches global memory (eliminates 128MB write + ~130MB read of the
// two-kernel pipeline — the R4-R10 plateau was traffic-bound at ~3.1 TB/s).
// Block 256 thr / 4 waves; wave owns 16 rows end-to-end; grid NPIX/64.
// Per 64-wide HID chunk:
//   W1 chunk in LDS (double-buffered, global_load_lds, gemm_blds-verified)
//   fc1 swapped-MFMA -> acc1 (thread: row=l16, 4 consecutive h-cols)
//   gelu -> pack -> WAVE-PRIVATE LDS exchange (16x72-pad rows; same-wave DS
//     ordering, no block barrier) -> fc2 A-frags (8 consecutive k per lane)
//   fc2 normal-MFMA into acc2[16] with W2 direct from L2 (R7-proven).
// W2 ks2=0 half preloaded BEFORE the W1-stage issue so its in-order vmcnt
// wait does not drain the stage.
__global__ __launch_bounds__(256, 2) void mlp_kernel(
    const u16* __restrict__ n2, const u16* __restrict__ f1F,
    const u16* __restrict__ f2F, const float* __restrict__ b1,
    const float* __restrict__ b2, const float* __restrict__ x1,
    float* __restrict__ out) {
  __shared__ u16 sW[2][16384];                 // W1 chunk dbuf, 2 x 32 KB
  __shared__ __align__(16) u16 hx[4][16][72];  // per-wave h exchange (pad 72)
  const int tid  = threadIdx.x;
  const int wave = tid >> 6, lane = tid & 63;
  const int quad = lane >> 4, l16 = lane & 15;
  const int m0w = blockIdx.x * 64 + wave * 16;   // wave's first row

  // n2 fragments: rows m0w..+15, full K=256. 32 VGPRs.
  const u16* aRow = n2 + (size_t)(m0w + l16) * CCH + quad * 8;
  bf16x8 afr[8];
#pragma unroll
  for (int ks = 0; ks < 8; ks++)
    afr[ks] = *(const bf16x8*)(aRow + ks * 32);

  auto stageW1 = [&](int hc, int buf) {
    const u16* g = f1F + (size_t)hc * 16384;   // 4 groups x 8 kb = 32 KB
#pragma unroll
    for (int i = 0; i < 8; i++)
      async16(g + i * 2048 + tid * 8, &sW[buf][i * 2048 + tid * 8]);
  };

  const u16* w2Base = f2F + lane * 8;

  floatx4 acc2[16];
#pragma unroll
  for (int gi2 = 0; gi2 < 16; gi2++) acc2[gi2] = (floatx4){0.f, 0.f, 0.f, 0.f};

  stageW1(0, 0);
#pragma unroll 1
  for (int hc = 0; hc < 16; ++hc) {
    __syncthreads();   // stageW1(hc) visible; all waves done with buf (hc+1)&1
    // W2 ks2=0 preload (oldest VMEM ops -> their wait leaves stage in flight)
    bf16x8 w2a[16];
#pragma unroll
    for (int gi2 = 0; gi2 < 16; gi2++)
      w2a[gi2] = *(const bf16x8*)(w2Base + (((size_t)gi2 * 32 + hc * 2) << 9));
    if (hc + 1 < 16) stageW1(hc + 1, (hc + 1) & 1);
    // bias1 for this chunk
    floatx4 bs1[4];
#pragma unroll
    for (int gi = 0; gi < 4; gi++)
      bs1[gi] = *(const floatx4*)&b1[hc * 64 + gi * 16 + quad * 4];
    // ---- fc1: h_chunk = n2 @ W1[:, hc*64..+64) ----
    const u16* sb = sW[hc & 1];
    floatx4 acc1[4];
#pragma unroll
    for (int gi = 0; gi < 4; gi++) acc1[gi] = (floatx4){0.f, 0.f, 0.f, 0.f};
#pragma unroll
    for (int ks = 0; ks < 8; ks++) {
      bf16x8 bfr[4];
#pragma unroll
      for (int gi = 0; gi < 4; gi++)
        bfr[gi] = *(const bf16x8*)&sb[(gi * 8 + ks) * 512 + lane * 8];
#pragma unroll
      for (int gi = 0; gi < 4; gi++)
        acc1[gi] = __builtin_amdgcn_mfma_f32_16x16x32_bf16(
            bfr[gi], afr[ks], acc1[gi], 0, 0, 0);   // swapped -> D^T
    }
    // ---- gelu + pack -> wave-private exchange ----
#pragma unroll
    for (int gi = 0; gi < 4; gi++) {
      float v[4];
#pragma unroll
      for (int r = 0; r < 4; r++) v[r] = gelu_fast(acc1[gi][r] + bs1[gi][r]);
      uint2 w;
      w.x = packbf(v[0], v[1]);
      w.y = packbf(v[2], v[3]);
      *(uint2*)&hx[wave][l16][gi * 16 + quad * 4] = w;   // row l16, cols +4
    }
    // same-wave DS ordering: reads below see the writes (compiler tracks the
    // shared-object dependency; LDS executes a wave's DS ops in order).
    bf16x8 hfrag[2];
#pragma unroll
    for (int ks2 = 0; ks2 < 2; ks2++)
      hfrag[ks2] = *(const bf16x8*)&hx[wave][l16][ks2 * 32 + quad * 8];
    // ---- fc2: acc2 += h_chunk @ W2[hc*64..+64, :] ----
#pragma unroll
    for (int gi2 = 0; gi2 < 16; gi2++)
      acc2[gi2] = __builtin_amdgcn_mfma_f32_16x16x32_bf16(
          hfrag[0], w2a[gi2], acc2[gi2], 0, 0, 0);
#pragma unroll
    for (int gi2 = 0; gi2 < 16; gi2++) {
      const bf16x8 w2b = *(const bf16x8*)(w2Base + (((size_t)gi2 * 32 + hc * 2 + 1) << 9));
      acc2[gi2] = __builtin_amdgcn_mfma_f32_16x16x32_bf16(
          hfrag[1], w2b, acc2[gi2], 0, 0, 0);
    }
  }

  // epilogue: rows m0w + quad*4 + r, col = gi2*16 + l16 (normal C layout).
#pragma unroll
  for (int gi2 = 0; gi2 < 16; gi2++) {
    const int col = gi2 * 16 + l16;
    const float bs = b2[col];
    const int row0 = m0w + quad * 4;
    floatx4 vv;
#pragma unroll
    for (int r = 0; r < 4; r++)
      vv[r] = acc2[gi2][r] + bs + x1[(size_t)(row0 + r) * CCH + col];
    *(floatx4*)&out[((size_t)((row0 >> 14) * CCH + col)) * HWSZ + (row0 & (HWSZ - 1))] = vv;
  }
}

// ---------------------------------------------------------------------------
extern "C" void kernel_launch(void* const* d_in, const int* in_sizes, int n_in,
                              void* d_out, int out_size, void* d_ws, size_t ws_size,
                              hipStream_t stream) {
  const float* x    = (const float*)d_in[0];
  const float* wq   = (const float*)d_in[1];
  const float* bq   = (const float*)d_in[2];
  const float* wk   = (const float*)d_in[3];
  const float* bk   = (const float*)d_in[4];
  const float* wv   = (const float*)d_in[5];
  const float* bv   = (const float*)d_in[6];
  const float* ln1g = (const float*)d_in[7];
  const float* ln1b = (const float*)d_in[8];
  const float* ln2g = (const float*)d_in[9];
  const float* ln2b = (const float*)d_in[10];
  const float* fc1w = (const float*)d_in[11];
  const float* fc1b = (const float*)d_in[12];
  const float* fc2w = (const float*)d_in[13];
  const float* fc2b = (const float*)d_in[14];
  float* out = (float*)d_out;

  // Workspace (aliased by liveness):
  //   [0,64)    x1 fp32               (res_ln2 -> mlp)
  //   [64,160)  qkv bf16 [N,768]      (qkv-gemm -> attn)
  //   [160,192) n1 / attn bf16        (ln1 -> qkv; attn -> res_ln2)
  //   [192,224) n2 bf16               (res_ln2 -> mlp)
  //   [224,..)  fragment-major bf16 weights + fused bias
  char* ws = (char*)d_ws;
  const size_t MB = (size_t)1 << 20;
  float* x1   = (float*)(ws);
  u16* qkv    = (u16*)(ws + 64 * MB);
  u16* n1     = (u16*)(ws + 160 * MB);
  u16* attnb  = n1;
  u16* n2     = (u16*)(ws + 192 * MB);
  u16* wqkvF  = (u16*)(ws + 224 * MB);      // frag-major [768 cols x 256 k]
  u16* f1F    = wqkvF + 768 * 256;          // frag-major [1024 cols x 256 k]
  u16* f2F    = f1F + 1024 * 256;           // frag-major [256 cols x 1024 k]
  float* bqkv = (float*)(f2F + 256 * 1024); // [768]

  dim3 blk(256);
  // weight prep: src w is [K_in, N_out] row-major fp32.
  // 256x256 weight: 16 g x 8 kb = 128 units -> 32 blocks; blob stride 65536 u16.
  wfrag_kernel<<<dim3(32),  blk, 0, stream>>>(wq,   wqkvF,          256, 256);
  wfrag_kernel<<<dim3(32),  blk, 0, stream>>>(wk,   wqkvF + 65536,  256, 256);
  wfrag_kernel<<<dim3(32),  blk, 0, stream>>>(wv,   wqkvF + 131072, 256, 256);
  wfrag_kernel<<<dim3(128), blk, 0, stream>>>(fc1w, f1F, 1024, 256);   // 64 g x 8 kb
  wfrag_kernel<<<dim3(128), blk, 0, stream>>>(fc2w, f2F, 256, 1024);   // 16 g x 32 kb
  concat_bias_kernel<<<dim3(3), blk, 0, stream>>>(bq, bk, bv, bqkv);

  ln1_kernel<<<NPIX / 32, blk, 0, stream>>>(x, ln1g, ln1b, n1);

  // fused QKV: [N,256] x frag(768,256) -> qkv [N,768]
  gemm_blds<12, 768, 0><<<dim3(NPIX / 128), blk, 0, stream>>>(n1, wqkvF, bqkv, qkv);

  attn_kernel<<<NPIX / 4, blk, 0, stream>>>(qkv, attnb);

  res_ln2_kernel<<<NPIX / 32, blk, 0, stream>>>(x, attnb, ln2g, ln2b, x1, n2);

  // fused MLP: n2 -> gelu(n2@W1+b1)@W2 + b2 + x1 -> out [B,C,H,W]
  mlp_kernel<<<dim3(NPIX / 64), blk, 0, stream>>>(n2, f1F, f2F, fc1b, fc2b, x1, out);
}

// Round 12
// 399.642 us; speedup vs baseline: 1.2462x; 1.2462x over previous
//
#include <hip/hip_runtime.h>
#include <hip/hip_bf16.h>
#include <math.h>

// Problem constants: B=4, C=D=256, H=W=128, HID=1024, N = B*H*W = 65536.
#define NPIX  65536
#define CCH   256
#define HWSZ  16384
#define WIDTH 128
#define HID   1024

typedef unsigned short u16;
typedef __bf16 bf16x8 __attribute__((ext_vector_type(8)));
typedef float  floatx4 __attribute__((ext_vector_type(4)));

__device__ __forceinline__ float bf2f(u16 u) {
  union { unsigned int i; float f; } c; c.i = ((unsigned int)u) << 16; return c.f;
}
__device__ __forceinline__ float bflo(unsigned int u) {
  union { unsigned int i; float f; } c; c.i = u << 16; return c.f;
}
__device__ __forceinline__ float bfhi(unsigned int u) {
  union { unsigned int i; float f; } c; c.i = u & 0xffff0000u; return c.f;
}
__device__ __forceinline__ u16 f2bf(float f) {
  union { float f; unsigned int i; } c; c.f = f;
  unsigned int x = c.i;
  x += 0x7fffu + ((x >> 16) & 1u);   // round-to-nearest-even
  return (u16)(x >> 16);
}
__device__ __forceinline__ unsigned int packbf(float lo, float hi) {
  return ((unsigned int)f2bf(hi) << 16) | (unsigned int)f2bf(lo);
}
__device__ __forceinline__ float fast_rcp(float x) {
  float r; asm("v_rcp_f32 %0, %1" : "=v"(r) : "v"(x)); return r;
}
__device__ __forceinline__ float fast_exp2(float x) {
  float r; asm("v_exp_f32 %0, %1" : "=v"(r) : "v"(x)); return r;   // 2^x
}
// gelu, tanh-approx form, algebraically = 0.5x(1+tanh(0.79788(x+0.044715x^3)))
//   = x * sigmoid(2t) = x / (1 + 2^(-x*(a*x^2 + b))),  a,b fold in 2*log2(e).
__device__ __forceinline__ float gelu_fast(float x) {
  const float u = x * x;
  const float s = x * fmaf(0.1029432f, u, 2.3022082f);
  const float e = fast_exp2(-s);      // v_exp_f32
  return x * fast_rcp(1.0f + e);      // v_rcp_f32 (no fdiv expansion)
}

// async global->LDS, 16B per lane; LDS dest is wave-uniform base + lane*16.
__device__ __forceinline__ void async16(const void* g, void* l) {
  __builtin_amdgcn_global_load_lds(
      (const __attribute__((address_space(1))) void*)g,
      (__attribute__((address_space(3))) void*)l, 16, 0, 0);
}

// ---------------------------------------------------------------------------
// Weight fp32 [K,N] -> fragment-major bf16 blob:
// unit u = g*(K/32) + kb   (g = 16-col group, kb = 32-k block); unit = 512 u16.
// dst[u*512 + lane*8 + e] = bf16(src[(kb*32 + (lane>>4)*8 + e)*N + g*16 + (lane&15)])
__global__ __launch_bounds__(256) void wfrag_kernel(
    const float* __restrict__ src, u16* __restrict__ dst, int N, int K) {
  const int tid = threadIdx.x;
  const int u = blockIdx.x * 4 + (tid >> 6);
  const int lane = tid & 63, quad = lane >> 4, l16 = lane & 15;
  const int K32 = K >> 5;
  const int g = u / K32, kb = u - g * K32;
  const int n = g * 16 + l16;
  const int k0 = kb * 32 + quad * 8;
  u16 tmp[8];
#pragma unroll
  for (int e = 0; e < 8; e++) tmp[e] = f2bf(src[(size_t)(k0 + e) * N + n]);
  *(bf16x8*)(dst + ((size_t)u * 64 + lane) * 8) = *(bf16x8*)tmp;
}

__global__ __launch_bounds__(256) void concat_bias_kernel(
    const float* __restrict__ bq, const float* __restrict__ bk,
    const float* __restrict__ bv, float* __restrict__ dst) {
  const int i = blockIdx.x * 256 + threadIdx.x;   // grid 3
  if (i < 256) dst[i] = bq[i];
  else if (i < 512) dst[i] = bk[i - 256];
  else if (i < 768) dst[i] = bv[i - 512];
}

// ---------------------------------------------------------------------------
// LayerNorm1: x [B,C,H,W] fp32 -> n1 [N,256] bf16
__global__ __launch_bounds__(256) void ln1_kernel(
    const float* __restrict__ x, const float* __restrict__ g,
    const float* __restrict__ bb, u16* __restrict__ n1) {
  __shared__ float sx[32][257];
  __shared__ float sred[16][32];
  __shared__ float sm[32], sr[32];
  const int tx = threadIdx.x;
  const int p0 = blockIdx.x * 32;
  {
    const int pix = tx & 31, cpart = tx >> 5;
    const int p = p0 + pix;
    const int b = p >> 14, hw = p & (HWSZ - 1);
    const float* xb = x + ((size_t)b * CCH) * HWSZ + hw;
    float s = 0.f, s2 = 0.f;
#pragma unroll 4
    for (int i = 0; i < 32; i++) {
      const int c = cpart * 32 + i;
      const float v = xb[(size_t)c * HWSZ];
      sx[pix][c] = v;
      s += v; s2 += v * v;
    }
    sred[cpart][pix] = s; sred[8 + cpart][pix] = s2;
  }
  __syncthreads();
  if (tx < 32) {
    float s = 0.f, s2 = 0.f;
#pragma unroll
    for (int j = 0; j < 8; j++) { s += sred[j][tx]; s2 += sred[8 + j][tx]; }
    const float m = s * (1.0f / 256.0f);
    const float var = s2 * (1.0f / 256.0f) - m * m;
    sm[tx] = m; sr[tx] = rsqrtf(var + 1e-5f);
  }
  __syncthreads();
  const float gc = g[tx], bc = bb[tx];
#pragma unroll 4
  for (int i = 0; i < 32; i++) {
    const float v = (sx[i][tx] - sm[i]) * sr[i] * gc + bc;
    n1[(size_t)(p0 + i) * CCH + tx] = f2bf(v);
  }
}

// ---------------------------------------------------------------------------
// Residual + LayerNorm2: x1 = x + attn (fp32 out), n2 = LN(x1) bf16
__global__ __launch_bounds__(256) void res_ln2_kernel(
    const float* __restrict__ x, const u16* __restrict__ attn,
    const float* __restrict__ g, const float* __restrict__ bb,
    float* __restrict__ x1, u16* __restrict__ n2) {
  __shared__ float sx[32][257];
  __shared__ float sred[16][32];
  __shared__ float sm[32], sr[32];
  const int tx = threadIdx.x;
  const int p0 = blockIdx.x * 32;
  {
    const int pix = tx & 31, cpart = tx >> 5;
    const int p = p0 + pix;
    const int b = p >> 14, hw = p & (HWSZ - 1);
    const float* xb = x + ((size_t)b * CCH) * HWSZ + hw;
#pragma unroll 4
    for (int i = 0; i < 32; i++) {
      const int c = cpart * 32 + i;
      sx[pix][c] = xb[(size_t)c * HWSZ];
    }
  }
  __syncthreads();
#pragma unroll 4
  for (int i = 0; i < 32; i++) {
    const float v = sx[i][tx] + bf2f(attn[(size_t)(p0 + i) * CCH + tx]);
    sx[i][tx] = v;
    x1[(size_t)(p0 + i) * CCH + tx] = v;
  }
  __syncthreads();
  {
    const int pix = tx & 31, cpart = tx >> 5;
    float s = 0.f, s2 = 0.f;
#pragma unroll 4
    for (int i = 0; i < 32; i++) {
      const float v = sx[pix][cpart * 32 + i];
      s += v; s2 += v * v;
    }
    sred[cpart][pix] = s; sred[8 + cpart][pix] = s2;
  }
  __syncthreads();
  if (tx < 32) {
    float s = 0.f, s2 = 0.f;
#pragma unroll
    for (int j = 0; j < 8; j++) { s += sred[j][tx]; s2 += sred[8 + j][tx]; }
    const float m = s * (1.0f / 256.0f);
    const float var = s2 * (1.0f / 256.0f) - m * m;
    sm[tx] = m; sr[tx] = rsqrtf(var + 1e-5f);
  }
  __syncthreads();
  const float gc = g[tx], bc = bb[tx];
#pragma unroll 4
  for (int i = 0; i < 32; i++) {
    const float v = (sx[i][tx] - sm[i]) * sr[i] * gc + bc;
    n2[(size_t)(p0 + i) * CCH + tx] = f2bf(v);
  }
}

// ---------------------------------------------------------------------------
// 3x3 neighborhood attention over fused qkv [N,768] (q|k|v per row).
__global__ __launch_bounds__(256) void attn_kernel(
    const u16* __restrict__ qkv, u16* __restrict__ attn) {
  const int tid = threadIdx.x;
  const int wave = tid >> 6, lane = tid & 63;
  const int p = blockIdx.x * 4 + wave;
  const int hw = p & (HWSZ - 1);
  const int hh = hw >> 7, ww = hw & (WIDTH - 1);
  const u16* rowp = qkv + (size_t)p * 768 + lane * 4;
  const uint2 qr = *(const uint2*)rowp;
  const float qf0 = bflo(qr.x), qf1 = bfhi(qr.x);
  const float qf2 = bflo(qr.y), qf3 = bfhi(qr.y);
  float sc[9];
#pragma unroll
  for (int n = 0; n < 9; n++) {
    const int dy = n / 3 - 1, dx = n % 3 - 1;
    const int y = hh + dy, x2 = ww + dx;
    float s = -1e30f;
    if (y >= 0 && y < 128 && x2 >= 0 && x2 < 128) {   // wave-uniform branch
      const uint2 kr = *(const uint2*)(rowp + 256 + (dy * WIDTH + dx) * 768);
      float d = qf0 * bflo(kr.x) + qf1 * bfhi(kr.x)
              + qf2 * bflo(kr.y) + qf3 * bfhi(kr.y);
#pragma unroll
      for (int o = 32; o >= 1; o >>= 1) d += __shfl_xor(d, o, 64);
      s = d * 0.0625f;   // 1/sqrt(256)
    }
    sc[n] = s;
  }
  float mx = sc[0];
#pragma unroll
  for (int n = 1; n < 9; n++) mx = fmaxf(mx, sc[n]);
  float wgt[9], wsum = 0.f;
#pragma unroll
  for (int n = 0; n < 9; n++) { wgt[n] = __expf(sc[n] - mx); wsum += wgt[n]; }
  const float inv = 1.0f / wsum;
  float a0 = 0.f, a1 = 0.f, a2 = 0.f, a3 = 0.f;
#pragma unroll
  for (int n = 0; n < 9; n++) {
    const int dy = n / 3 - 1, dx = n % 3 - 1;
    const int y = hh + dy, x2 = ww + dx;
    if (y >= 0 && y < 128 && x2 >= 0 && x2 < 128) {
      const uint2 vr = *(const uint2*)(rowp + 512 + (dy * WIDTH + dx) * 768);
      const float wn = wgt[n] * inv;
      a0 += wn * bflo(vr.x); a1 += wn * bfhi(vr.x);
      a2 += wn * bflo(vr.y); a3 += wn * bfhi(vr.y);
    }
  }
  uint2 o;
  o.x = ((unsigned int)f2bf(a1) << 16) | (unsigned int)f2bf(a0);
  o.y = ((unsigned int)f2bf(a3) << 16) | (unsigned int)f2bf(a2);
  *(uint2*)(attn + (size_t)p * CCH + lane * 4) = o;
}

// ---------------------------------------------------------------------------
// GEMM with B in double-buffered LDS (staged via global_load_lds) and whole-K
// A in registers. 128-row blocks (4 waves x 32 rows), K=256, 64-col chunks.
// Swapped MFMA operands -> D^T layout; dwordx2 packed stores.
// Counted vmcnt(8) barriers (verified R9). Used for the fused QKV GEMM.
template <int NCH, int NST, int EPI>
__global__ __launch_bounds__(256, 3) void gemm_blds(
    const u16* __restrict__ A, const u16* __restrict__ wf,
    const float* __restrict__ bias, u16* __restrict__ outb) {
  __shared__ u16 sB[2][16384];    // 2 x 32 KB
  const int tid  = threadIdx.x;
  const int wave = tid >> 6, lane = tid & 63;
  const int quad = lane >> 4, l16 = lane & 15;
  const int m0 = blockIdx.x * 128 + wave * 32;

  // A fragments: rows m0..m0+31, full K=256. 64 VGPRs.
  const u16* aRow = A + (size_t)(m0 + l16) * CCH + quad * 8;
  bf16x8 afr[2][8];
#pragma unroll
  for (int mi = 0; mi < 2; mi++)
#pragma unroll
    for (int ks = 0; ks < 8; ks++)
      afr[mi][ks] = *(const bf16x8*)(aRow + (size_t)mi * 16 * CCH + ks * 32);

  // output row pointers (transposed-acc layout: row = m0 + mi*16 + l16)
  u16* rowPtr0 = outb + (size_t)(m0 + l16) * NST;
  u16* rowPtr1 = rowPtr0 + (size_t)16 * NST;

  auto stage = [&](int ch, int buf) {
    const u16* g = wf + (size_t)ch * 16384;    // chunk = 4 groups x 8 kb = 32 KB
#pragma unroll
    for (int i = 0; i < 8; i++)
      async16(g + i * 2048 + tid * 8, &sB[buf][i * 2048 + tid * 8]);
  };

  stage(0, 0);
#pragma unroll 1
  for (int ch = 0; ch < NCH; ++ch) {
    if (ch == 0) asm volatile("s_waitcnt vmcnt(0)" ::: "memory");
    else         asm volatile("s_waitcnt vmcnt(8)" ::: "memory");
    __builtin_amdgcn_s_barrier();
    __builtin_amdgcn_sched_barrier(0);
    floatx4 bs4pre[4];
#pragma unroll
    for (int gi = 0; gi < 4; gi++)
      bs4pre[gi] = *(const floatx4*)&bias[ch * 64 + gi * 16 + quad * 4];
    if (ch + 1 < NCH) stage(ch + 1, (ch + 1) & 1);
    __builtin_amdgcn_sched_barrier(0);
    const u16* sb = sB[ch & 1];
    floatx4 acc[2][4];
#pragma unroll
    for (int mi = 0; mi < 2; mi++)
#pragma unroll
      for (int gi = 0; gi < 4; gi++) acc[mi][gi] = (floatx4){0.f, 0.f, 0.f, 0.f};
#pragma unroll
    for (int ks = 0; ks < 8; ks++) {
      bf16x8 bfr[4];
#pragma unroll
      for (int gi = 0; gi < 4; gi++)
        bfr[gi] = *(const bf16x8*)&sb[(gi * 8 + ks) * 512 + lane * 8];
#pragma unroll
      for (int mi = 0; mi < 2; mi++)
#pragma unroll
        for (int gi = 0; gi < 4; gi++)
          acc[mi][gi] = __builtin_amdgcn_mfma_f32_16x16x32_bf16(
              bfr[gi], afr[mi][ks], acc[mi][gi], 0, 0, 0);   // swapped -> D^T
    }
#pragma unroll
    for (int gi = 0; gi < 4; gi++) {
      const int colb = ch * 64 + gi * 16 + quad * 4;
      const floatx4 bs4 = bs4pre[gi];
#pragma unroll
      for (int mi = 0; mi < 2; mi++) {
        float v[4];
#pragma unroll
        for (int r = 0; r < 4; r++) {
          float val = acc[mi][gi][r] + bs4[r];
          if constexpr (EPI == 1) val = gelu_fast(val);
          v[r] = val;
        }
        uint2 w;
        w.x = packbf(v[0], v[1]);
        w.y = packbf(v[2], v[3]);
        *(uint2*)((mi == 0 ? rowPtr0 : rowPtr1) + colb) = w;
      }
    }
  }
}

// ---------------------------------------------------------------------------
// FUSED MLP v2 (block-cooperative): out = x1 + gelu(n2@W1+b1)@W2 + b2.
// h never touches HBM. Block 256 thr / 4 waves / 64 rows; grid NPIX/64.
// Per 64-wide HID chunk (2 barriers, 32 MFMA/wave per phase):
//   bar1 -> w2 preload (wave's OWN 4 col-groups only — fixes R11's 4x W2
//   duplication) -> fc1: wave's 16 rows, swapped-MFMA (R11-verified math)
//   -> gelu -> write block-shared hL[64][72] -> bar2 -> stage W1(hc+1)
//   (covered by fc2) -> fc2: all 64 rows x wave's 64 cols, normal MFMA
//   (operand layout identical to R10-verified fc2), acc2[4][4].
// LDS 74.7 KB -> 2 blocks/CU. hL pad 72 -> 2-way banks (~free, m136).
__global__ __launch_bounds__(256, 2) void mlp_kernel(
    const u16* __restrict__ n2, const u16* __restrict__ f1F,
    const u16* __restrict__ f2F, const float* __restrict__ b1,
    const float* __restrict__ b2, const float* __restrict__ x1,
    float* __restrict__ out) {
  __shared__ u16 sW[2][16384];                 // W1 chunk dbuf, 2 x 32 KB
  __shared__ __align__(16) u16 hL[64][72];     // block h exchange, 9.2 KB
  const int tid  = threadIdx.x;
  const int wave = tid >> 6, lane = tid & 63;
  const int quad = lane >> 4, l16 = lane & 15;
  const int mblk = blockIdx.x * 64;
  const int m0w  = mblk + wave * 16;           // fc1 rows for this wave

  // n2 fragments: rows m0w..+15, full K=256. 32 VGPRs.
  const u16* aRow = n2 + (size_t)(m0w + l16) * CCH + quad * 8;
  bf16x8 afr[8];
#pragma unroll
  for (int ks = 0; ks < 8; ks++)
    afr[ks] = *(const bf16x8*)(aRow + ks * 32);

  auto stageW1 = [&](int hc, int buf) {
    const u16* g = f1F + (size_t)hc * 16384;   // 4 groups x 8 kb = 32 KB
#pragma unroll
    for (int i = 0; i < 8; i++)
      async16(g + i * 2048 + tid * 8, &sW[buf][i * 2048 + tid * 8]);
  };

  // W2 base for this wave's 4 col-groups (g = wave*4 + gi), blob unit
  // = g*32 + kb (512 u16 each); lane reads its 16B fragment.
  const u16* w2Base = f2F + (((size_t)(wave * 4)) << 14) + lane * 8;

  floatx4 acc2[4][4];
#pragma unroll
  for (int mi = 0; mi < 4; mi++)
#pragma unroll
    for (int gi = 0; gi < 4; gi++) acc2[mi][gi] = (floatx4){0.f, 0.f, 0.f, 0.f};

  stageW1(0, 0);
#pragma unroll 1
  for (int hc = 0; hc < 16; ++hc) {
    __syncthreads();   // bar1: sW[hc&1] staged+visible; hL free (fc2 done)
    // W2 preload (L2): consumed in fc2, covered by fc1's 32 MFMA.
    bf16x8 w2f[4][2];
#pragma unroll
    for (int gi = 0; gi < 4; gi++)
#pragma unroll
      for (int ks2 = 0; ks2 < 2; ks2++)
        w2f[gi][ks2] = *(const bf16x8*)(w2Base + (((size_t)gi * 32 + hc * 2 + ks2) << 9));
    floatx4 bs1[4];
#pragma unroll
    for (int gi = 0; gi < 4; gi++)
      bs1[gi] = *(const floatx4*)&b1[hc * 64 + gi * 16 + quad * 4];
    // ---- fc1: h_chunk = n2 @ W1[:, hc*64..+64) for wave's 16 rows ----
    const u16* sb = sW[hc & 1];
    floatx4 acc1[4];
#pragma unroll
    for (int gi = 0; gi < 4; gi++) acc1[gi] = (floatx4){0.f, 0.f, 0.f, 0.f};
#pragma unroll
    for (int ks = 0; ks < 8; ks++) {
      bf16x8 bfr[4];
#pragma unroll
      for (int gi = 0; gi < 4; gi++)
        bfr[gi] = *(const bf16x8*)&sb[(gi * 8 + ks) * 512 + lane * 8];
#pragma unroll
      for (int gi = 0; gi < 4; gi++)
        acc1[gi] = __builtin_amdgcn_mfma_f32_16x16x32_bf16(
            bfr[gi], afr[ks], acc1[gi], 0, 0, 0);   // swapped -> D^T
    }
    // ---- gelu + pack -> block-shared exchange (row = wave*16+l16) ----
#pragma unroll
    for (int gi = 0; gi < 4; gi++) {
      float v[4];
#pragma unroll
      for (int r = 0; r < 4; r++) v[r] = gelu_fast(acc1[gi][r] + bs1[gi][r]);
      uint2 w;
      w.x = packbf(v[0], v[1]);
      w.y = packbf(v[2], v[3]);
      *(uint2*)&hL[wave * 16 + l16][gi * 16 + quad * 4] = w;
    }
    __syncthreads();   // bar2: hL complete (lgkmcnt drained by syncthreads)
    if (hc + 1 < 16) stageW1(hc + 1, (hc + 1) & 1);   // covered by fc2
    // ---- fc2: acc2 += h[64 rows] @ W2[hc*64..+64, wave's 64 cols] ----
#pragma unroll
    for (int mi = 0; mi < 4; mi++)
#pragma unroll
      for (int ks2 = 0; ks2 < 2; ks2++) {
        const bf16x8 hf = *(const bf16x8*)&hL[mi * 16 + l16][ks2 * 32 + quad * 8];
#pragma unroll
        for (int gi = 0; gi < 4; gi++)
          acc2[mi][gi] = __builtin_amdgcn_mfma_f32_16x16x32_bf16(
              hf, w2f[gi][ks2], acc2[mi][gi], 0, 0, 0);
      }
  }

  // epilogue: row = mblk + mi*16 + quad*4 + r, col = (wave*4+gi)*16 + l16.
#pragma unroll
  for (int mi = 0; mi < 4; mi++)
#pragma unroll
    for (int gi = 0; gi < 4; gi++) {
      const int col = (wave * 4 + gi) * 16 + l16;
      const float bs = b2[col];
      const int row0 = mblk + mi * 16 + quad * 4;
      floatx4 vv;
#pragma unroll
      for (int r = 0; r < 4; r++)
        vv[r] = acc2[mi][gi][r] + bs + x1[(size_t)(row0 + r) * CCH + col];
      *(floatx4*)&out[((size_t)((row0 >> 14) * CCH + col)) * HWSZ + (row0 & (HWSZ - 1))] = vv;
    }
}

// ---------------------------------------------------------------------------
extern "C" void kernel_launch(void* const* d_in, const int* in_sizes, int n_in,
                              void* d_out, int out_size, void* d_ws, size_t ws_size,
                              hipStream_t stream) {
  const float* x    = (const float*)d_in[0];
  const float* wq   = (const float*)d_in[1];
  const float* bq   = (const float*)d_in[2];
  const float* wk   = (const float*)d_in[3];
  const float* bk   = (const float*)d_in[4];
  const float* wv   = (const float*)d_in[5];
  const float* bv   = (const float*)d_in[6];
  const float* ln1g = (const float*)d_in[7];
  const float* ln1b = (const float*)d_in[8];
  const float* ln2g = (const float*)d_in[9];
  const float* ln2b = (const float*)d_in[10];
  const float* fc1w = (const float*)d_in[11];
  const float* fc1b = (const float*)d_in[12];
  const float* fc2w = (const float*)d_in[13];
  const float* fc2b = (const float*)d_in[14];
  float* out = (float*)d_out;

  // Workspace (aliased by liveness):
  //   [0,64)    x1 fp32               (res_ln2 -> mlp)
  //   [64,160)  qkv bf16 [N,768]      (qkv-gemm -> attn)
  //   [160,192) n1 / attn bf16        (ln1 -> qkv; attn -> res_ln2)
  //   [192,224) n2 bf16               (res_ln2 -> mlp)
  //   [224,..)  fragment-major bf16 weights + fused bias
  char* ws = (char*)d_ws;
  const size_t MB = (size_t)1 << 20;
  float* x1   = (float*)(ws);
  u16* qkv    = (u16*)(ws + 64 * MB);
  u16* n1     = (u16*)(ws + 160 * MB);
  u16* attnb  = n1;
  u16* n2     = (u16*)(ws + 192 * MB);
  u16* wqkvF  = (u16*)(ws + 224 * MB);      // frag-major [768 cols x 256 k]
  u16* f1F    = wqkvF + 768 * 256;          // frag-major [1024 cols x 256 k]
  u16* f2F    = f1F + 1024 * 256;           // frag-major [256 cols x 1024 k]
  float* bqkv = (float*)(f2F + 256 * 1024); // [768]

  dim3 blk(256);
  // weight prep: src w is [K_in, N_out] row-major fp32.
  // 256x256 weight: 16 g x 8 kb = 128 units -> 32 blocks; blob stride 65536 u16.
  wfrag_kernel<<<dim3(32),  blk, 0, stream>>>(wq,   wqkvF,          256, 256);
  wfrag_kernel<<<dim3(32),  blk, 0, stream>>>(wk,   wqkvF + 65536,  256, 256);
  wfrag_kernel<<<dim3(32),  blk, 0, stream>>>(wv,   wqkvF + 131072, 256, 256);
  wfrag_kernel<<<dim3(128), blk, 0, stream>>>(fc1w, f1F, 1024, 256);   // 64 g x 8 kb
  wfrag_kernel<<<dim3(128), blk, 0, stream>>>(fc2w, f2F, 256, 1024);   // 16 g x 32 kb
  concat_bias_kernel<<<dim3(3), blk, 0, stream>>>(bq, bk, bv, bqkv);

  ln1_kernel<<<NPIX / 32, blk, 0, stream>>>(x, ln1g, ln1b, n1);

  // fused QKV: [N,256] x frag(768,256) -> qkv [N,768]
  gemm_blds<12, 768, 0><<<dim3(NPIX / 128), blk, 0, stream>>>(n1, wqkvF, bqkv, qkv);

  attn_kernel<<<NPIX / 4, blk, 0, stream>>>(qkv, attnb);

  res_ln2_kernel<<<NPIX / 32, blk, 0, stream>>>(x, attnb, ln2g, ln2b, x1, n2);

  // fused MLP: n2 -> gelu(n2@W1+b1)@W2 + b2 + x1 -> out [B,C,H,W]
  mlp_kernel<<<dim3(NPIX / 64), blk, 0, stream>>>(n2, f1F, f2F, fc1b, fc2b, x1, out);
}